// Round 16
// baseline (496.173 us; speedup 1.0000x reference)
//
#include <hip/hip_runtime.h>

#define BQ 256
#define TQ 1024
#define FQ 37
#define UQ 64
#define G3 192
#define CH 8
#define NCK (TQ / CH)
#define CFD (CH * FQ)   // 296 dwords per staged chunk

typedef float v2f __attribute__((ext_vector_type(2)));

__device__ __forceinline__ float sigmoid_f(float x) {
    return 1.0f / (1.0f + __expf(-x));
}
__device__ __forceinline__ float tanh_f(float x) {
    return 1.0f - 2.0f / (__expf(2.0f * x) + 1.0f);
}

#define PINP4(A, I) asm volatile("" : "+v"(A[I]), "+v"(A[I+1]), \
    "+v"(A[I+2]), "+v"(A[I+3]))

// R15 + the AGPR-parking fix. Diagnosis: VGPR_Count frozen at 148 (= producer
// demand) across R9-R15 while the consumer needs 192 weight regs + ~80 working
// set > 256 arch cap -> allocator parks weights in AGPRs (unified file; not in
// VGPR_Count; no scratch) and feeds each inline-asm "v" operand via
// v_accvgpr_read copies INSIDE the loop (~200-400 cy/step — why R14's FMA
// halving was a no-op). Fix: (a) re-pin weight pairs once per chunk inside the
// k-loop (zero insts, forces arch residency across the body); (b) shrink
// working set: half-B broadcast reads interleaved into half-A consumption
// (reuse ha[q] right after its 6 pk_fma; also hides B's LDS latency under A's
// FMA stream). Accumulation order bit-identical to R15.
__global__ __launch_bounds__(128)
__attribute__((amdgpu_waves_per_eu(1, 1)))
void gru_ldsb2(const float* __restrict__ values,   // [B,T,F]
               const int*   __restrict__ lengths,  // [B]
               const float* __restrict__ Wk,       // [F,3U]
               const float* __restrict__ Wr,       // [U,3U]
               const float* __restrict__ bias,     // [2,3U]
               const float* __restrict__ dw,       // [U]
               const float* __restrict__ db,       // [1]
               float*       __restrict__ out)      // [B,T]
{
    const int tid = threadIdx.x;
    const int j   = tid & 63;
    const int w   = tid >> 6;
    const int b   = blockIdx.x;

    __shared__ __align__(16) float s_v[2][CH][40];   // staged values (dbuf)
    __shared__ float s_xp[2][CH][G3];                // x-projections (dbuf)
    __shared__ __align__(16) float s_h8[2][CH][76];  // h history (padded rows)

    const float* vbp = values + (size_t)b * TQ * FQ;
    float* ob = out + (size_t)b * TQ;

    if (w == 0) {
        // ================= CONSUMER =================
        v2f Pz[32], Pr[32], Ph[32];      // weight pairs over u: {W[2i], W[2i+1]}
#pragma unroll
        for (int i = 0; i < 32; ++i) {
            v2f tz, tr, th;
            tz.x = Wr[(2 * i) * G3 + j];        tz.y = Wr[(2 * i + 1) * G3 + j];
            tr.x = Wr[(2 * i) * G3 + 64 + j];   tr.y = Wr[(2 * i + 1) * G3 + 64 + j];
            th.x = Wr[(2 * i) * G3 + 128 + j];  th.y = Wr[(2 * i + 1) * G3 + 128 + j];
            Pz[i] = tz; Pr[i] = tr; Ph[i] = th;
        }

        const float bh = bias[G3 + 128 + j];     // h-gate recurrent bias
        const int len = lengths[b];

        s_h8[1][7][j] = 0.0f;                    // t=0 broadcast slot (h0 = 0)
        asm volatile("s_waitcnt lgkmcnt(0)" ::: "memory");
        __builtin_amdgcn_s_barrier();            // prologue barrier

        float h = 0.0f;                          // lane j holds h_j
        const float* hprev = &s_h8[1][7][0];     // uniform row of previous h

#pragma unroll 1
        for (int k = 0; k < NCK; ++k) {
            const int pb = k & 1;
            const int tbase = k * CH;
            // ---- in-loop pins: weights must be in ARCH VGPRs across this body
#pragma unroll
            for (int i = 0; i < 32; i += 4) { PINP4(Pz, i); PINP4(Pr, i); PINP4(Ph, i); }
#pragma unroll 1
            for (int tc = 0; tc < CH; ++tc) {
                const float xz = s_xp[pb][tc][j];
                const float xr = s_xp[pb][tc][64 + j];
                const float xh = s_xp[pb][tc][128 + j];

                const float4* hp4 = (const float4*)hprev;
                v2f azp; azp.x = 0.f; azp.y = 0.f;
                v2f arp; arp.x = 0.f; arp.y = 0.f;
                v2f ahp; ahp.x = 0.f; ahp.y = 0.f;

#define PKF(ACC, WP, HV) asm("v_pk_fma_f32 %0, %1, %2, %0" \
        : "+v"(ACC) : "v"(WP), "v"(HV));

                float4 ha[8];
                // issue all 8 half-A uniform b128 reads (HW broadcast)
#pragma unroll
                for (int q = 0; q < 8; ++q) ha[q] = hp4[q];
                // consume half-A; immediately reuse ha[q] to ISSUE its half-B
                // read (B latency hides under remaining A consumption)
#pragma unroll
                for (int q = 0; q < 8; ++q) {
                    const v2f* hv = (const v2f*)&ha[q];
                    PKF(azp, Pz[2 * q],     hv[0])
                    PKF(arp, Pr[2 * q],     hv[0])
                    PKF(ahp, Ph[2 * q],     hv[0])
                    PKF(azp, Pz[2 * q + 1], hv[1])
                    PKF(arp, Pr[2 * q + 1], hv[1])
                    PKF(ahp, Ph[2 * q + 1], hv[1])
                    ha[q] = hp4[8 + q];          // issue B read for this slot
                }
                // consume half-B
#pragma unroll
                for (int q = 0; q < 8; ++q) {
                    const v2f* hv = (const v2f*)&ha[q];
                    PKF(azp, Pz[16 + 2 * q],     hv[0])
                    PKF(arp, Pr[16 + 2 * q],     hv[0])
                    PKF(ahp, Ph[16 + 2 * q],     hv[0])
                    PKF(azp, Pz[16 + 2 * q + 1], hv[1])
                    PKF(arp, Pr[16 + 2 * q + 1], hv[1])
                    PKF(ahp, Ph[16 + 2 * q + 1], hv[1])
                }
#undef PKF
                // horizontal adds: same grouping as R15 -> bit-identical
                const float az = azp.x + azp.y;
                const float ar = arp.x + arp.y;
                const float ah = ahp.x + ahp.y;

                const float z  = sigmoid_f(xz + az);
                const float r  = sigmoid_f(xr + ar);
                const float cc = tanh_f(xh + r * (bh + ah));
                const float hn = z * h + (1.0f - z) * cc;
                h = ((tbase + tc) < len) ? hn : h;
                s_h8[pb][tc][j] = h;             // broadcast source + head input
                asm volatile("s_waitcnt lgkmcnt(0)" ::: "memory");
                hprev = &s_h8[pb][tc][0];
            }
            __builtin_amdgcn_s_barrier();        // once per 8 steps
        }
    } else {
        // ================= PRODUCER (verbatim R15) =================
        float Kz[FQ], Kr[FQ], Kh[FQ];
#pragma unroll
        for (int f = 0; f < FQ; ++f) {
            Kz[f] = Wk[f * G3 + j];
            Kr[f] = Wk[f * G3 + 64 + j];
            Kh[f] = Wk[f * G3 + 128 + j];
        }
        const float bz  = bias[j] + bias[G3 + j];            // fold rec bias z
        const float br  = bias[64 + j] + bias[G3 + 64 + j];  // fold rec bias r
        const float bhx = bias[128 + j];                     // input bias only
        const float dbv = db[0];
        float dwv[8];
#pragma unroll
        for (int i = 0; i < 8; ++i) dwv[i] = dw[(j & 7) * 8 + i];

        int rq[5], cq[5];
        bool act[5];
        float stg[5];
#pragma unroll
        for (int q = 0; q < 5; ++q) {
            const int idx = j + 64 * q;
            act[q] = idx < CFD;
            rq[q] = idx / FQ;
            cq[q] = idx - rq[q] * FQ;
            stg[q] = 0.0f;
        }

#define STAGE_LOAD(CK)                                                        \
        _Pragma("unroll")                                                     \
        for (int q = 0; q < 5; ++q)                                           \
            if (act[q]) stg[q] = vbp[(size_t)(CK) * CFD + j + 64 * q];
#define STAGE_WRITE(SB)                                                       \
        _Pragma("unroll")                                                     \
        for (int q = 0; q < 5; ++q)                                           \
            if (act[q]) s_v[SB][rq[q]][cq[q]] = stg[q];

#define XF(VAL, I) { az += (VAL) * Kz[I]; ar += (VAL) * Kr[I]; ah += (VAL) * Kh[I]; }
#define XPROW(BB)                                                             \
    _Pragma("unroll 1")                                                       \
    for (int row = 0; row < CH; ++row) {                                      \
        const float4* vr = (const float4*)&s_v[BB][row][0];                   \
        float az = bz, ar = br, ah = bhx;                                     \
        { float4 v0 = vr[0], v1 = vr[1], v2 = vr[2];                          \
          XF(v0.x, 0)  XF(v0.y, 1)  XF(v0.z, 2)  XF(v0.w, 3)                  \
          XF(v1.x, 4)  XF(v1.y, 5)  XF(v1.z, 6)  XF(v1.w, 7)                  \
          XF(v2.x, 8)  XF(v2.y, 9)  XF(v2.z, 10) XF(v2.w, 11) }               \
        { float4 v3 = vr[3], v4 = vr[4], v5 = vr[5];                          \
          XF(v3.x, 12) XF(v3.y, 13) XF(v3.z, 14) XF(v3.w, 15)                 \
          XF(v4.x, 16) XF(v4.y, 17) XF(v4.z, 18) XF(v4.w, 19)                 \
          XF(v5.x, 20) XF(v5.y, 21) XF(v5.z, 22) XF(v5.w, 23) }               \
        { float4 v6 = vr[6], v7 = vr[7], v8 = vr[8];                          \
          float f36 = s_v[BB][row][36];                                       \
          XF(v6.x, 24) XF(v6.y, 25) XF(v6.z, 26) XF(v6.w, 27)                 \
          XF(v7.x, 28) XF(v7.y, 29) XF(v7.z, 30) XF(v7.w, 31)                 \
          XF(v8.x, 32) XF(v8.y, 33) XF(v8.z, 34) XF(v8.w, 35)                 \
          XF(f36, 36) }                                                       \
        s_xp[BB][row][j]       = az;                                          \
        s_xp[BB][row][64 + j]  = ar;                                          \
        s_xp[BB][row][128 + j] = ah;                                          \
    }

#define HEAD(HB, TB)                                                          \
    {                                                                         \
        const int e = j & 7, s = j >> 3;                                      \
        const float4* hr = (const float4*)&s_h8[HB][s][e * 8];                \
        float4 ha = hr[0], hc = hr[1];                                        \
        float pp = ha.x * dwv[0] + ha.y * dwv[1] + ha.z * dwv[2]              \
                 + ha.w * dwv[3] + hc.x * dwv[4] + hc.y * dwv[5]              \
                 + hc.z * dwv[6] + hc.w * dwv[7];                             \
        pp += __shfl_xor(pp, 1, 64);                                          \
        pp += __shfl_xor(pp, 2, 64);                                          \
        pp += __shfl_xor(pp, 4, 64);                                          \
        if (e == 0) ob[(TB) + s] = sigmoid_f(pp + dbv);                       \
    }

        // prologue: chunk0 -> s_v[0]; chunk1 -> s_v[1]; issue chunk2; xp(chunk0)
        STAGE_LOAD(0)
        asm volatile("s_waitcnt vmcnt(0)" ::: "memory");
        STAGE_WRITE(0)
        STAGE_LOAD(1)
        asm volatile("s_waitcnt vmcnt(0)" ::: "memory");
        STAGE_WRITE(1)
        STAGE_LOAD(2)
        asm volatile("s_waitcnt lgkmcnt(0)" ::: "memory");  // own s_v visible
        XPROW(0)
        asm volatile("s_waitcnt lgkmcnt(0)" ::: "memory");
        __builtin_amdgcn_s_barrier();            // prologue barrier

#pragma unroll 1
        for (int k = 0; k < NCK; ++k) {
            const int pb = k & 1, nb = pb ^ 1;
            if (k > 0) HEAD(nb, (k - 1) * CH)
            if (k + 2 < NCK) {
                asm volatile("s_waitcnt vmcnt(0)" ::: "memory");
                STAGE_WRITE(pb)                  // chunk k+2
                if (k + 3 < NCK) STAGE_LOAD(k + 3)
            }
            if (k + 1 < NCK) XPROW(nb)           // xp chunk k+1 from s_v[nb]
            asm volatile("s_waitcnt lgkmcnt(0)" ::: "memory");
            __builtin_amdgcn_s_barrier();        // once per 8 steps
        }
        HEAD((NCK - 1) & 1, (NCK - 1) * CH)      // after final barrier: race-free

#undef STAGE_LOAD
#undef STAGE_WRITE
#undef XF
#undef XPROW
#undef HEAD
    }
}

extern "C" void kernel_launch(void* const* d_in, const int* in_sizes, int n_in,
                              void* d_out, int out_size, void* d_ws, size_t ws_size,
                              hipStream_t stream) {
    const float* values  = (const float*)d_in[2];
    const int*   lengths = (const int*)  d_in[4];
    const float* Wk      = (const float*)d_in[5];
    const float* Wr      = (const float*)d_in[6];
    const float* bias    = (const float*)d_in[7];
    const float* dw      = (const float*)d_in[8];
    const float* db      = (const float*)d_in[9];
    float* out = (float*)d_out;

    gru_ldsb2<<<dim3(BQ), dim3(128), 0, stream>>>(
        values, lengths, Wk, Wr, bias, dw, db, out);
}